// Round 9
// baseline (284.731 us; speedup 1.0000x reference)
//
#include <hip/hip_runtime.h>
#include <math.h>

// Problem constants (match reference)
#define B_ 2048
#define L_ 200
#define V_ 50000
#define D_ 300
#define H_ 128
#define C_ 20

// d_ws layout: rep [B_][600] floats at offset 0 (4,915,200 B);
// done[256] counters at byte offset 5 MiB (zeroed via hipMemsetAsync).
#define REP_FLOATS (B_ * 2 * D_)
#define DONE_OFF   (5u * 1024u * 1024u)

// LDS union: gather phase (8.0 KB) vs mlp phase (23.4 KB). One allocation,
// phases are strictly sequential within a block.
union Smem {
    struct {
        int    idx[L_];
        float4 sum[225];
        float4 mx[225];
    } g;
    struct {
        float4 rep[8][150];      // 8 rows x 150 quads = 19.2 KB
        float  h[8][H_ + 4];     // padded rows, 528 B each (16B-aligned)
    } m;
};

// -----------------------------------------------------------------------------
// Fused persistent kernel. Phase A (all 2048 blocks): per-batch-row gather +
// sum/max (R1..R8-proven: ~73us, 3.45 TB/s fabric plateau, FETCH 245 MB) ->
// rep[b] in global. Then __threadfence + atomicAdd(done[b>>3]). The 8th
// finisher of each 8-row group acquires and runs the MLP for that group
// in the same block -- overlapping MLP with other groups' gathers and
// eliminating the serialized second dispatch (R5-R8: ~17-20us, invariant
// across 3 mlp rewrites => dispatch/drain cost, not compute).
// -----------------------------------------------------------------------------
__global__ __launch_bounds__(256) void fused_persist_kernel(
    const int* __restrict__ x,        // [B][L]
    const int* __restrict__ lengths,  // [B]
    const float* __restrict__ emb,    // [V][D]
    const float* __restrict__ W_new,  // [H][2D]
    const float* __restrict__ b_new,  // [H]
    const float* __restrict__ W3,     // [C][H]
    const float* __restrict__ b3,     // [C]
    float* __restrict__ rep,          // [B][2D] scratch
    int* __restrict__ done,           // [256] group counters (pre-zeroed)
    float* __restrict__ out)          // [B][C]
{
    __shared__ Smem s;
    __shared__ int s_doer;

    const int b = blockIdx.x;
    const int t = threadIdx.x;

    // ---- Phase A: gather + reduce for batch row b (UNCHANGED control) ----
    if (t < L_) s.g.idx[t] = x[b * L_ + t];
    __syncthreads();

    if (t < 225) {
        const int g = t / 75;       // 0..2
        const int p = t - g * 75;   // 0..74
        float4 s4 = make_float4(0.f, 0.f, 0.f, 0.f);
        float4 m4 = make_float4(-INFINITY, -INFINITY, -INFINITY, -INFINITY);
        #pragma unroll 4
        for (int l = g; l < L_; l += 3) {
            const float4 v =
                *(const float4*)(emb + (size_t)s.g.idx[l] * D_ + (p << 2));
            s4.x += v.x; s4.y += v.y; s4.z += v.z; s4.w += v.w;
            m4.x = fmaxf(m4.x, v.x); m4.y = fmaxf(m4.y, v.y);
            m4.z = fmaxf(m4.z, v.z); m4.w = fmaxf(m4.w, v.w);
        }
        s.g.sum[t] = s4;
        s.g.mx[t]  = m4;
    }
    __syncthreads();

    if (t < 75) {
        const float4 sa = s.g.sum[t], sb = s.g.sum[t + 75], sc = s.g.sum[t + 150];
        const float4 ma = s.g.mx[t],  mb = s.g.mx[t + 75],  mc = s.g.mx[t + 150];
        const float lf = (float)lengths[b];
        const float inv = 1.0f / (lf * lf);   // reference bug: sum / len^2
        float4 S, M;
        S.x = (sa.x + sb.x + sc.x) * inv;
        S.y = (sa.y + sb.y + sc.y) * inv;
        S.z = (sa.z + sb.z + sc.z) * inv;
        S.w = (sa.w + sb.w + sc.w) * inv;
        M.x = fmaxf(fmaxf(ma.x, mb.x), mc.x);
        M.y = fmaxf(fmaxf(ma.y, mb.y), mc.y);
        M.z = fmaxf(fmaxf(ma.z, mb.z), mc.z);
        M.w = fmaxf(fmaxf(ma.w, mb.w), mc.w);
        float4* o = (float4*)(rep + (size_t)b * (2 * D_));
        o[t]      = S;   // mean_bug part
        o[75 + t] = M;   // max part
    }
    __syncthreads();

    // ---- Group completion: 8th finisher of group (b>>3) does the MLP ----
    if (t == 0) {
        __threadfence();                              // release rep[b]
        const int old = atomicAdd(&done[b >> 3], 1);  // device-scope
        s_doer = (old == 7) ? 1 : 0;
    }
    __syncthreads();
    if (!s_doer) return;
    if (t == 0) __threadfence();                      // acquire others' rep
    __syncthreads();

    // ---- Phase B (doer only): MLP for group rows [8g, 8g+8) ----
    const int row0 = (b >> 3) * 8;

    // Stage 8 rep rows (1200 quads) into LDS, coalesced.
    {
        const float4* src = (const float4*)(rep + (size_t)row0 * (2 * D_));
        float4* dst = &s.m.rep[0][0];
        #pragma unroll
        for (int i = 0; i < 5; ++i) {
            const int j = t + (i << 8);
            if (j < 1200) dst[j] = src[j];
        }
    }
    __syncthreads();

    // Layer 1: 4-lane k-cluster owns cols c0 = t>>2 and c0+64; 8 rows each.
    const int lane2 = t & 3;
    const int c0 = t >> 2;
    const int c1 = c0 + 64;

    float acc0[8] = {0.f, 0.f, 0.f, 0.f, 0.f, 0.f, 0.f, 0.f};
    float acc1[8] = {0.f, 0.f, 0.f, 0.f, 0.f, 0.f, 0.f, 0.f};

    const float4* w0row = (const float4*)(W_new + (size_t)c0 * (2 * D_));
    const float4* w1row = (const float4*)(W_new + (size_t)c1 * (2 * D_));

    #pragma unroll 2
    for (int i = 0; i < 38; ++i) {
        const int q = lane2 + (i << 2);
        if (q < 150) {   // compile-time true for i<=36
            const float4 wa = w0row[q];
            const float4 wb = w1row[q];
            #pragma unroll
            for (int r = 0; r < 8; ++r) {
                const float4 rq = s.m.rep[r][q];
                acc0[r] = fmaf(wa.x, rq.x, acc0[r]);
                acc0[r] = fmaf(wa.y, rq.y, acc0[r]);
                acc0[r] = fmaf(wa.z, rq.z, acc0[r]);
                acc0[r] = fmaf(wa.w, rq.w, acc0[r]);
                acc1[r] = fmaf(wb.x, rq.x, acc1[r]);
                acc1[r] = fmaf(wb.y, rq.y, acc1[r]);
                acc1[r] = fmaf(wb.z, rq.z, acc1[r]);
                acc1[r] = fmaf(wb.w, rq.w, acc1[r]);
            }
        }
    }

    const float bn0 = b_new[c0];
    const float bn1 = b_new[c1];
    #pragma unroll
    for (int r = 0; r < 8; ++r) {
        float a0 = acc0[r];
        a0 += __shfl_xor(a0, 1);
        a0 += __shfl_xor(a0, 2);
        float a1 = acc1[r];
        a1 += __shfl_xor(a1, 1);
        a1 += __shfl_xor(a1, 2);
        if (lane2 == 0) {
            s.m.h[r][c0] = fmaxf(a0 + bn0, 0.f);
            s.m.h[r][c1] = fmaxf(a1 + bn1, 0.f);
        }
    }
    __syncthreads();

    // Layer 2: out = h @ W3^T + b3 (8 rows x 20 cols = 160 outputs)
    if (t < 8 * C_) {
        const int r = t / C_;
        const int cc = t - r * C_;
        const float4* w3 = (const float4*)(W3 + cc * H_);
        const float4* h4 = (const float4*)&s.m.h[r][0];
        float acc2 = b3[cc];
        #pragma unroll 8
        for (int k = 0; k < 32; ++k) {
            const float4 wv = w3[k];
            const float4 hv = h4[k];
            acc2 = fmaf(hv.x, wv.x, acc2);
            acc2 = fmaf(hv.y, wv.y, acc2);
            acc2 = fmaf(hv.z, wv.z, acc2);
            acc2 = fmaf(hv.w, wv.w, acc2);
        }
        out[(size_t)(row0 + r) * C_ + cc] = acc2;
    }
}

// -----------------------------------------------------------------------------
extern "C" void kernel_launch(void* const* d_in, const int* in_sizes, int n_in,
                              void* d_out, int out_size, void* d_ws, size_t ws_size,
                              hipStream_t stream) {
    const int*   x       = (const int*)  d_in[0];
    const int*   lengths = (const int*)  d_in[1];
    const float* emb     = (const float*)d_in[2];
    const float* W_new   = (const float*)d_in[3];
    const float* b_new   = (const float*)d_in[4];
    const float* W3      = (const float*)d_in[5];
    const float* b3      = (const float*)d_in[6];
    float* out  = (float*)d_out;
    float* rep  = (float*)d_ws;                              // 4.92 MB
    int*   done = (int*)((char*)d_ws + DONE_OFF);            // 256 counters

    // Zero the group counters (ws is re-poisoned to 0xAA before every launch).
    hipMemsetAsync(done, 0, 256 * sizeof(int), stream);

    fused_persist_kernel<<<B_, 256, 0, stream>>>(
        x, lengths, emb, W_new, b_new, W3, b3, rep, done, out);
}

// Round 10
// 174.257 us; speedup vs baseline: 1.6340x; 1.6340x over previous
//
#include <hip/hip_runtime.h>
#include <math.h>

// Problem constants (match reference)
#define B_ 2048
#define L_ 200
#define V_ 50000
#define D_ 300
#define H_ 128
#define C_ 20

// -----------------------------------------------------------------------------
// Kernel 1: per-batch-row embedding gather + sum/max. R1..R8-proven control:
// ~73-77 us, FETCH 245 MB, 3.45-3.55 TB/s; at the logical-byte roofline
// (491 MB / 6.3 TB/s achievable = 78 us ideal; cache hits put effective
// service at 6.7 TB/s). One block per batch row; 225 lanes = 3 L-groups x 75
// float4-quads, coalesced 16B/lane. Writes rep[b][0:300]=sum/len^2
// (reference bug preserved), rep[b][300:600]=max. UNCHANGED.
// R9 lesson: do NOT add device-scope fences/atomics here — __threadfence's
// L2 writeback/invalidate (non-coherent per-XCD L2) destroyed the emb
// table's L2 residency and tripled gather time.
// -----------------------------------------------------------------------------
__global__ __launch_bounds__(256, 4) void gather_reduce_kernel(
    const int* __restrict__ x,        // [B][L]
    const int* __restrict__ lengths,  // [B]
    const float* __restrict__ emb,    // [V][D]
    float* __restrict__ rep)          // [B][2D]
{
    __shared__ int s_idx[L_];
    __shared__ float4 s_sum[225];
    __shared__ float4 s_max[225];

    const int b = blockIdx.x;
    const int t = threadIdx.x;

    if (t < L_) s_idx[t] = x[b * L_ + t];
    __syncthreads();

    if (t < 225) {
        const int g = t / 75;       // 0..2
        const int p = t - g * 75;   // 0..74
        float4 s4 = make_float4(0.f, 0.f, 0.f, 0.f);
        float4 m4 = make_float4(-INFINITY, -INFINITY, -INFINITY, -INFINITY);
        #pragma unroll 4
        for (int l = g; l < L_; l += 3) {
            const float4 v =
                *(const float4*)(emb + (size_t)s_idx[l] * D_ + (p << 2));
            s4.x += v.x; s4.y += v.y; s4.z += v.z; s4.w += v.w;
            m4.x = fmaxf(m4.x, v.x); m4.y = fmaxf(m4.y, v.y);
            m4.z = fmaxf(m4.z, v.z); m4.w = fmaxf(m4.w, v.w);
        }
        s_sum[t] = s4;
        s_max[t] = m4;
    }
    __syncthreads();

    if (t < 75) {
        const float4 sa = s_sum[t], sb = s_sum[t + 75], sc = s_sum[t + 150];
        const float4 ma = s_max[t], mb = s_max[t + 75], mc = s_max[t + 150];
        const float lf = (float)lengths[b];
        const float inv = 1.0f / (lf * lf);   // reference bug: sum / len^2
        float4 S, M;
        S.x = (sa.x + sb.x + sc.x) * inv;
        S.y = (sa.y + sb.y + sc.y) * inv;
        S.z = (sa.z + sb.z + sc.z) * inv;
        S.w = (sa.w + sb.w + sc.w) * inv;
        M.x = fmaxf(fmaxf(ma.x, mb.x), mc.x);
        M.y = fmaxf(fmaxf(ma.y, mb.y), mc.y);
        M.z = fmaxf(fmaxf(ma.z, mb.z), mc.z);
        M.w = fmaxf(fmaxf(ma.w, mb.w), mc.w);
        float4* o = (float4*)(rep + (size_t)b * (2 * D_));
        o[t]      = S;   // mean_bug part, d = 4t..4t+3
        o[75 + t] = M;   // max part, d = 300+4t..300+4t+3
    }
}

// -----------------------------------------------------------------------------
// Kernel 2 (v5): row-tiled fused MLP. 512 blocks x 512 threads, 4 rows/block
// (2 blocks/CU -> 4 waves/SIMD TLP, finer tail drain than v4's 1/CU).
// 16-lane k-cluster (lane16 = t&15), cluster cg = t>>4 (0..31) owns 4 cols
// {cg, cg+32, cg+64, cg+96}. Per K-step: 4 coalesced W-quad loads (256B per
// cluster-group; W_new read once per block = 157 MB L2 total ~ 4.6 us
// aggregate) + 4 rep LDS reads reused across 4 cols + 64 FMA.
// Combine via __shfl_xor 1/2/4/8 (inside 16-lane group).
// -----------------------------------------------------------------------------
__global__ __launch_bounds__(512) void mlp4_kernel(
    const float* __restrict__ rep,    // [B][2D]
    const float* __restrict__ W_new,  // [H][2D]
    const float* __restrict__ b_new,  // [H]
    const float* __restrict__ W3,     // [C][H]
    const float* __restrict__ b3,     // [C]
    float* __restrict__ out)          // [B][C]
{
    __shared__ float4 s_rep[4][150];      // 9.6 KB
    __shared__ float  s_h[4][H_ + 4];     // padded rows, 528 B (16B-aligned)

    const int t = threadIdx.x;
    const int row0 = blockIdx.x * 4;

    // Stage 4 rep rows (contiguous 2400 floats = 600 float4), coalesced.
    {
        const float4* src = (const float4*)(rep + (size_t)row0 * (2 * D_));
        float4* dst = &s_rep[0][0];
        #pragma unroll
        for (int i = 0; i < 2; ++i) {
            const int j = t + (i << 9);
            if (j < 600) dst[j] = src[j];   // 600 = 512 + 88
        }
    }
    __syncthreads();

    // ---- Layer 1: h = relu(W_new @ rep + b_new) ----
    const int lane16 = t & 15;   // k-subgroup within 16-lane cluster
    const int cg = t >> 4;       // cluster 0..31

    float acc[4][4];             // [col j][row r], all compile-time indexed
    #pragma unroll
    for (int j = 0; j < 4; ++j)
        #pragma unroll
        for (int r = 0; r < 4; ++r) acc[j][r] = 0.f;

    const float4* w0  = (const float4*)(W_new + (size_t)(cg     ) * (2 * D_));
    const float4* w1  = (const float4*)(W_new + (size_t)(cg + 32) * (2 * D_));
    const float4* w2  = (const float4*)(W_new + (size_t)(cg + 64) * (2 * D_));
    const float4* w3r = (const float4*)(W_new + (size_t)(cg + 96) * (2 * D_));

    #pragma unroll
    for (int i = 0; i < 10; ++i) {
        const int q = lane16 + (i << 4);
        if (q < 150) {   // compile-time true for i<9; runtime only at i=9
            const float4 wa = w0[q];
            const float4 wb = w1[q];
            const float4 wc = w2[q];
            const float4 wd = w3r[q];
            #pragma unroll
            for (int r = 0; r < 4; ++r) {
                const float4 rq = s_rep[r][q];
                acc[0][r] = fmaf(wa.x, rq.x, acc[0][r]);
                acc[0][r] = fmaf(wa.y, rq.y, acc[0][r]);
                acc[0][r] = fmaf(wa.z, rq.z, acc[0][r]);
                acc[0][r] = fmaf(wa.w, rq.w, acc[0][r]);
                acc[1][r] = fmaf(wb.x, rq.x, acc[1][r]);
                acc[1][r] = fmaf(wb.y, rq.y, acc[1][r]);
                acc[1][r] = fmaf(wb.z, rq.z, acc[1][r]);
                acc[1][r] = fmaf(wb.w, rq.w, acc[1][r]);
                acc[2][r] = fmaf(wc.x, rq.x, acc[2][r]);
                acc[2][r] = fmaf(wc.y, rq.y, acc[2][r]);
                acc[2][r] = fmaf(wc.z, rq.z, acc[2][r]);
                acc[2][r] = fmaf(wc.w, rq.w, acc[2][r]);
                acc[3][r] = fmaf(wd.x, rq.x, acc[3][r]);
                acc[3][r] = fmaf(wd.y, rq.y, acc[3][r]);
                acc[3][r] = fmaf(wd.z, rq.z, acc[3][r]);
                acc[3][r] = fmaf(wd.w, rq.w, acc[3][r]);
            }
        }
    }

    // combine the 16 k-subgroups (xor 1/2/4/8 stays inside 16-lane group)
    #pragma unroll
    for (int j = 0; j < 4; ++j) {
        const int c = cg + (j << 5);
        const float bn = b_new[c];
        #pragma unroll
        for (int r = 0; r < 4; ++r) {
            float a = acc[j][r];
            a += __shfl_xor(a, 1);
            a += __shfl_xor(a, 2);
            a += __shfl_xor(a, 4);
            a += __shfl_xor(a, 8);
            if (lane16 == 0) s_h[r][c] = fmaxf(a + bn, 0.f);
        }
    }
    __syncthreads();

    // ---- Layer 2: out = h @ W3^T + b3 (4 rows x 20 cols = 80 outputs) ----
    if (t < 4 * C_) {
        const int r = t / C_;
        const int cc = t - r * C_;
        const float4* w3 = (const float4*)(W3 + cc * H_);
        const float4* h4 = (const float4*)&s_h[r][0];
        float acc2 = b3[cc];
        #pragma unroll 8
        for (int k = 0; k < 32; ++k) {
            const float4 wv = w3[k];
            const float4 hv = h4[k];
            acc2 = fmaf(hv.x, wv.x, acc2);
            acc2 = fmaf(hv.y, wv.y, acc2);
            acc2 = fmaf(hv.z, wv.z, acc2);
            acc2 = fmaf(hv.w, wv.w, acc2);
        }
        out[(size_t)(row0 + r) * C_ + cc] = acc2;
    }
}

// -----------------------------------------------------------------------------
extern "C" void kernel_launch(void* const* d_in, const int* in_sizes, int n_in,
                              void* d_out, int out_size, void* d_ws, size_t ws_size,
                              hipStream_t stream) {
    const int*   x       = (const int*)  d_in[0];
    const int*   lengths = (const int*)  d_in[1];
    const float* emb     = (const float*)d_in[2];
    const float* W_new   = (const float*)d_in[3];
    const float* b_new   = (const float*)d_in[4];
    const float* W3      = (const float*)d_in[5];
    const float* b3      = (const float*)d_in[6];
    float* out = (float*)d_out;
    float* rep = (float*)d_ws;   // [B][600] = 4.92 MB scratch

    gather_reduce_kernel<<<B_, 256, 0, stream>>>(x, lengths, emb, rep);
    mlp4_kernel<<<B_ / 4, 512, 0, stream>>>(rep, W_new, b_new, W3, b3, out);
}